// Round 19
// baseline (68.877 us; speedup 1.0000x reference)
//
#include <hip/hip_runtime.h>
#include <hip/hip_bf16.h>

// score = sigmoid(relu([h[src]|h[dst]]@W1 + b1) @ W2 + b2)
// R19: R17 base (best measured, 67.1us) + two K1 levers:
//   (a) launch_bounds (256,3): ~85 VGPR cap >= ~80 live, 12 waves/CU (was 8)
//   (b) 4-col pack epilogue: 2 shfl_xor levels -> 8-B uint2 stores from
//       quarter-lanes (16 store instrs/wave, was 32 x 4-B)
//   K0: W1 -> frag table (R9 exact). K2: R8 exact (42.2-42.6us gather wall:
//   FETCH 133MB @ ~3.3TB/s beyond-L2, null response to occupancy/in-flight).

#define HID    128
#define NNODE  50000
#define NEDGE  600000
#define NGRP   ((NNODE + 31) / 32)       // 1563 node groups of 32
#define K2BLK  2048
#define UVBYTES ((size_t)NNODE * 256 * 2)   // 25.6 MB
#define WTFRAG_OFF UVBYTES                  // frag-ordered W1T, 64 KB

typedef __attribute__((ext_vector_type(8)))  __bf16 bf16x8;
typedef __attribute__((ext_vector_type(16))) float  f32x16;

static __device__ __forceinline__ unsigned int pack2bf(float a, float b) {
    unsigned int ua = __float_as_uint(a);
    unsigned int ub = __float_as_uint(b);
    ua = (ua + 0x7FFFu + ((ua >> 16) & 1u)) >> 16;
    ub = (ub + 0x7FFFu + ((ub >> 16) & 1u)) >> 16;
    return (ub << 16) | (ua & 0xFFFFu);
}

// ---------------- K0: W1 -> bf16 fragment-ordered table (R9 exact) ----------
__global__ __launch_bounds__(256, 1) void w1_frag_kernel(
    const float* __restrict__ W1, unsigned short* __restrict__ w1tf)
{
    const int T = blockIdx.x * 256 + threadIdx.x;   // 4096 threads
    const int l31  = T & 31;
    const int FIDX = T >> 5;
    const int l5 = FIDX & 1, ks = (FIDX >> 1) & 7;
    const int ct = (FIDX >> 4) & 3, colhalf = FIDX >> 6;
    const int kb = colhalf * 128 + ks * 16 + l5 * 8;
    const int n  = ct * 32 + l31;
    bf16x8 v;
#pragma unroll
    for (int j = 0; j < 8; ++j) v[j] = (__bf16)W1[(kb + j) * HID + n];
    *(bf16x8*)(w1tf + (size_t)T * 8) = v;
}

// ---------------- K1: node GEMM, dense-staged h tile ----------------
__global__ __launch_bounds__(256, 3) void node_gemm_kernel(
    const float* __restrict__ h, const unsigned short* __restrict__ w1tf,
    const float* __restrict__ b1, unsigned short* __restrict__ uvs)
{
    // A tile: 32 rows x 128 bf16 = 256 B/row, 8 KB. 16B slots XOR-swizzled
    // by (row&7)<<4 (bijective within the 256-B row).
    __shared__ unsigned char smem[8192];

    const int t = threadIdx.x, lane = t & 63, wv = t >> 6;
    const int l31 = lane & 31, l5 = lane >> 5;
    const int group = blockIdx.x;

    // ---- stage h tile: DENSE. task tau: row r=tau>>4, slot s=tau&15.
    {
        const float* hb = h + (size_t)group * 32 * HID;
        const bool tail = (group == NGRP - 1);
#pragma unroll
        for (int it = 0; it < 2; ++it) {
            const int tau = it * 256 + t;
            const int r = tau >> 4, s = tau & 15;
            const float* src_;
            if (tail) {
                const int node = group * 32 + r;
                const int rc = (node < NNODE) ? r : (NNODE - 1 - group * 32);
                src_ = hb + rc * HID + s * 8;
            } else {
                src_ = hb + tau * 8;
            }
            float4 f0 = *(const float4*)src_;
            float4 f1 = *(const float4*)(src_ + 4);
            bf16x8 v;
            v[0] = (__bf16)f0.x; v[1] = (__bf16)f0.y;
            v[2] = (__bf16)f0.z; v[3] = (__bf16)f0.w;
            v[4] = (__bf16)f1.x; v[5] = (__bf16)f1.y;
            v[6] = (__bf16)f1.z; v[7] = (__bf16)f1.w;
            *(bf16x8*)(smem + r * 256 + ((s * 16) ^ ((r & 7) << 4))) = v;
        }
    }
    __syncthreads();

    const int colhalf = wv >> 1;            // 0 -> u cols, 1 -> v cols
    const int ctpair  = wv & 1;             // 64-col slice within the half

    float b1v[2];
#pragma unroll
    for (int cc = 0; cc < 2; ++cc)
        b1v[cc] = (colhalf == 0) ? b1[(ctpair * 2 + cc) * 32 + l31] : 0.0f;

    f32x16 acc[2];
#pragma unroll
    for (int cc = 0; cc < 2; ++cc)
#pragma unroll
        for (int r = 0; r < 16; ++r) acc[cc][r] = 0.0f;

    const int abase = l31 * 256;
    const int aswz  = (l31 & 7) << 4;

#pragma unroll
    for (int ks = 0; ks < 8; ++ks) {
        // A-frag: row=l31, k = ks*16 + l5*8 + j -> byte off ks*32 + l5*16
        bf16x8 af = *(const bf16x8*)(smem + abase +
                                     ((ks * 32 + l5 * 16) ^ aswz));
#pragma unroll
        for (int cc = 0; cc < 2; ++cc) {
            const int fidx = ((colhalf * 4 + ctpair * 2 + cc) * 8 + ks) * 2 + l5;
            bf16x8 bfg = *(const bf16x8*)(w1tf + (size_t)fidx * 256 + l31 * 8);
            acc[cc] = __builtin_amdgcn_mfma_f32_32x32x16_bf16(af, bfg,
                                                              acc[cc], 0, 0, 0);
        }
    }

    // store epilogue: C row rr=(r&3)+8*(r>>2)+4*l5 (node), col = colhalf*128
    // + (ctpair*2+cc)*32 + l31. 4-col pack: lane L (L%4==0) gathers cols
    // L,L+1,L+2,L+3 of its row via 2 shfl levels -> one 8-B uint2 store.
#pragma unroll
    for (int cc = 0; cc < 2; ++cc) {
#pragma unroll
        for (int r = 0; r < 16; ++r) {
            float mine = acc[cc][r] + b1v[cc];
            float p1 = __shfl_xor(mine, 1);             // col ^1
            unsigned int w01 = pack2bf(mine, p1);       // valid on even l31
            unsigned int w23 = __shfl_xor(w01, 2);      // cols +2,+3 (on l31%4==0)
            if (!(l31 & 3)) {
                const int rr = (r & 3) + 8 * (r >> 2) + 4 * l5;
                const int nd = group * 32 + rr;
                if (nd < NNODE) {
                    const int n = colhalf * 128 + (ctpair * 2 + cc) * 32 + l31;
                    uint2 w; w.x = w01; w.y = w23;
                    *(uint2*)(uvs + (size_t)nd * 256 + n) = w;
                }
            }
        }
    }
}

// ---------------- K2: edge gather + tiny MLP tail (R8 exact) ----------------
__global__ __launch_bounds__(256, 8) void edge_score_kernel(
    const unsigned short* __restrict__ uvs,
    const float* __restrict__ W2, const float* __restrict__ b2,
    const int* __restrict__ src, const int* __restrict__ dst,
    float* __restrict__ out)
{
    const int t = threadIdx.x, lane = t & 63, wv = t >> 6;
    const int c = lane & 15;        // 16-B chunk within 128-col half
    const int g = lane >> 4;        // edge-in-quad 0..3

    bool idx64;
    {
        unsigned long long m =
            __ballot((src[2 * lane + 1] == 0) && (dst[2 * lane + 1] == 0));
        idx64 = (m == ~0ULL);
    }

    float w2f[8];
#pragma unroll
    for (int j = 0; j < 8; ++j) w2f[j] = W2[c * 8 + j];
    const float b2s = b2[0];

    const int gw = blockIdx.x * 4 + wv;
    const int NW = K2BLK * 4;
    const int NQ = NEDGE / 4;

    for (int q0 = gw; q0 < NQ; q0 += 2 * NW) {
        const int q1  = q0 + NW;
        const int q1c = q1 < NQ ? q1 : NQ - 1;
        const int e0  = q0 * 4 + g;
        const int e1  = q1c * 4 + g;

        const int ns0 = idx64 ? src[2 * e0] : src[e0];
        const int nd0 = idx64 ? dst[2 * e0] : dst[e0];
        const int ns1 = idx64 ? src[2 * e1] : src[e1];
        const int nd1 = idx64 ? dst[2 * e1] : dst[e1];

        const uint4 qu0 = *(const uint4*)(uvs + (size_t)ns0 * 256 + c * 8);
        const uint4 qv0 = *(const uint4*)(uvs + (size_t)nd0 * 256 + 128 + c * 8);
        const uint4 qu1 = *(const uint4*)(uvs + (size_t)ns1 * 256 + c * 8);
        const uint4 qv1 = *(const uint4*)(uvs + (size_t)nd1 * 256 + 128 + c * 8);

#pragma unroll
        for (int half = 0; half < 2; ++half) {
            const uint4 qu = half ? qu1 : qu0;
            const uint4 qv = half ? qv1 : qv0;
            float p = 0.0f;
#pragma unroll
            for (int j = 0; j < 4; ++j) {
                const unsigned int uw = j == 0 ? qu.x : j == 1 ? qu.y
                                      : j == 2 ? qu.z : qu.w;
                const unsigned int vw = j == 0 ? qv.x : j == 1 ? qv.y
                                      : j == 2 ? qv.z : qv.w;
                float slo = __uint_as_float(uw << 16)
                          + __uint_as_float(vw << 16);
                float shi = __uint_as_float(uw & 0xFFFF0000u)
                          + __uint_as_float(vw & 0xFFFF0000u);
                slo = slo > 0.0f ? slo : 0.0f;
                shi = shi > 0.0f ? shi : 0.0f;
                p = fmaf(slo, w2f[2 * j], p);
                p = fmaf(shi, w2f[2 * j + 1], p);
            }
            p += __shfl_xor(p, 1);
            p += __shfl_xor(p, 2);
            p += __shfl_xor(p, 4);
            p += __shfl_xor(p, 8);

            if (c == 0 && (half == 0 || q1 < NQ)) {
                const int e = half ? e1 : e0;
                out[e] = 1.0f / (1.0f + __expf(-(p + b2s)));
            }
        }
    }
}

// ---------------- fallback (proven single-kernel) ----------------
__global__ __launch_bounds__(256, 1) void edge_mlp_fallback(
    const float* __restrict__ h,  const float* __restrict__ W1,
    const float* __restrict__ b1, const float* __restrict__ W2,
    const float* __restrict__ b2, const int* __restrict__ src,
    const int* __restrict__ dst,  float* __restrict__ out)
{
    __shared__ unsigned char smem[65536];
    const int t = threadIdx.x, lane = t & 63, wv = t >> 6;
    const int l31 = lane & 31, l5 = lane >> 5;
    bool idx64;
    {
        unsigned long long m =
            __ballot((src[2 * lane + 1] == 0) && (dst[2 * lane + 1] == 0));
        idx64 = (m == ~0ULL);
    }
    for (int task = t; task < 4096; task += 256) {
        int n = task & 127, slot = task >> 7;
        const float* wp = W1 + (slot * 8) * HID + n;
        bf16x8 v;
#pragma unroll
        for (int j = 0; j < 8; ++j) v[j] = (__bf16)wp[j * HID];
        *(bf16x8*)(smem + n * 512 + ((slot * 16) ^ ((n & 31) << 4))) = v;
    }
    float b1v[4], w2v[4];
#pragma unroll
    for (int ct = 0; ct < 4; ++ct) {
        int n = ct * 32 + l31;
        b1v[ct] = b1[n]; w2v[ct] = W2[n];
    }
    const float b2s = b2[0];
    __syncthreads();
    const int swz = l31 << 4;
    const int gw = blockIdx.x * 4 + wv;
    for (int tile = gw; tile < NEDGE / 32; tile += 512 * 4) {
        const int e = tile * 32 + l31;
        const long long ns = idx64 ? (long long)src[2 * e] : (long long)src[e];
        const long long nd = idx64 ? (long long)dst[2 * e] : (long long)dst[e];
        const float* hs = h + ns * HID + l5 * 8;
        const float* hd = h + nd * HID + l5 * 8;
        f32x16 acc[4];
#pragma unroll
        for (int ct = 0; ct < 4; ++ct)
#pragma unroll
            for (int r = 0; r < 16; ++r) acc[ct][r] = 0.0f;
#pragma unroll
        for (int ks = 0; ks < 16; ++ks) {
            const float* p = (ks < 8) ? (hs + ks * 16) : (hd + (ks - 8) * 16);
            float4 f0 = *(const float4*)p;
            float4 f1 = *(const float4*)(p + 4);
            bf16x8 af;
            af[0] = (__bf16)f0.x; af[1] = (__bf16)f0.y;
            af[2] = (__bf16)f0.z; af[3] = (__bf16)f0.w;
            af[4] = (__bf16)f1.x; af[5] = (__bf16)f1.y;
            af[6] = (__bf16)f1.z; af[7] = (__bf16)f1.w;
            const int coff = ks * 32 + l5 * 16;
#pragma unroll
            for (int ct = 0; ct < 4; ++ct) {
                const int n = ct * 32 + l31;
                bf16x8 bfg = *(const bf16x8*)(smem + n * 512 + (coff ^ swz));
                acc[ct] = __builtin_amdgcn_mfma_f32_32x32x16_bf16(af, bfg,
                                                                  acc[ct], 0, 0, 0);
            }
        }
        float p[16];
#pragma unroll
        for (int r = 0; r < 16; ++r) p[r] = 0.0f;
#pragma unroll
        for (int ct = 0; ct < 4; ++ct)
#pragma unroll
            for (int r = 0; r < 16; ++r) {
                float v = acc[ct][r] + b1v[ct];
                v = v > 0.0f ? v : 0.0f;
                p[r] += v * w2v[ct];
            }
#pragma unroll
        for (int r = 0; r < 16; ++r) {
            p[r] += __shfl_xor(p[r], 1);  p[r] += __shfl_xor(p[r], 2);
            p[r] += __shfl_xor(p[r], 4);  p[r] += __shfl_xor(p[r], 8);
            p[r] += __shfl_xor(p[r], 16);
        }
        if (l31 == 0) {
#pragma unroll
            for (int g = 0; g < 4; ++g) {
                const int e0 = tile * 32 + g * 8 + l5 * 4;
                float4 o4;
                o4.x = 1.0f / (1.0f + __expf(-(p[4 * g + 0] + b2s)));
                o4.y = 1.0f / (1.0f + __expf(-(p[4 * g + 1] + b2s)));
                o4.z = 1.0f / (1.0f + __expf(-(p[4 * g + 2] + b2s)));
                o4.w = 1.0f / (1.0f + __expf(-(p[4 * g + 3] + b2s)));
                *(float4*)(out + e0) = o4;
            }
        }
    }
}

extern "C" void kernel_launch(void* const* d_in, const int* in_sizes, int n_in,
                              void* d_out, int out_size, void* d_ws, size_t ws_size,
                              hipStream_t stream) {
    const float* h  = (const float*)d_in[0];
    const float* W1 = (const float*)d_in[1];
    const float* b1 = (const float*)d_in[2];
    const float* W2 = (const float*)d_in[3];
    const float* b2 = (const float*)d_in[4];
    const int* src  = (const int*)d_in[5];
    const int* dst  = (const int*)d_in[6];
    (void)in_sizes; (void)n_in; (void)out_size;

    const size_t need = WTFRAG_OFF + 65536;
    if (ws_size >= need) {
        unsigned short* uvs  = (unsigned short*)d_ws;
        unsigned short* w1tf = (unsigned short*)((char*)d_ws + WTFRAG_OFF);
        w1_frag_kernel<<<16, 256, 0, stream>>>(W1, w1tf);
        node_gemm_kernel<<<NGRP, 256, 0, stream>>>(h, w1tf, b1, uvs);
        edge_score_kernel<<<K2BLK, 256, 0, stream>>>(uvs, W2, b2, src, dst,
                                                     (float*)d_out);
    } else {
        edge_mlp_fallback<<<512, 256, 0, stream>>>(h, W1, b1, W2, b2, src, dst,
                                                   (float*)d_out);
    }
}

// Round 20
// 66.991 us; speedup vs baseline: 1.0282x; 1.0282x over previous
//
#include <hip/hip_runtime.h>
#include <hip/hip_bf16.h>

// score = sigmoid(relu([h[src]|h[dst]]@W1 + b1) @ W2 + b2)
// R20 = R17 exact (measured best, 67.1us). Terminal configuration:
//   K0: W1 -> bf16 fragment-ordered table (64 KB, L2-hot).
//   K1: dense-staged h tile (contiguous 16 KB/block stream -> swizzled LDS
//       -> ds_read_b128 A-frags; B-frags from frag table). (256,2).
//   K2: R8 edge gather (42.2-42.6us random-gather fabric wall: FETCH 133MB
//       @ ~3.3TB/s beyond-L2; null response to occupancy/in-flight/split).
// Evidence: R18 (merge K0) +0.8us, R19 (occupancy+store pack) +1.8us,
// R11 (2x in-flight) +2us, R13/R14 (K1 re-parallelize / coop fusion) flat/bad.

#define HID    128
#define NNODE  50000
#define NEDGE  600000
#define NGRP   ((NNODE + 31) / 32)       // 1563 node groups of 32
#define K2BLK  2048
#define UVBYTES ((size_t)NNODE * 256 * 2)   // 25.6 MB
#define WTFRAG_OFF UVBYTES                  // frag-ordered W1T, 64 KB

typedef __attribute__((ext_vector_type(8)))  __bf16 bf16x8;
typedef __attribute__((ext_vector_type(16))) float  f32x16;

static __device__ __forceinline__ unsigned int pack2bf(float a, float b) {
    unsigned int ua = __float_as_uint(a);
    unsigned int ub = __float_as_uint(b);
    ua = (ua + 0x7FFFu + ((ua >> 16) & 1u)) >> 16;
    ub = (ub + 0x7FFFu + ((ub >> 16) & 1u)) >> 16;
    return (ub << 16) | (ua & 0xFFFFu);
}

// ---------------- K0: W1 -> bf16 fragment-ordered table ----------------
__global__ __launch_bounds__(256, 1) void w1_frag_kernel(
    const float* __restrict__ W1, unsigned short* __restrict__ w1tf)
{
    const int T = blockIdx.x * 256 + threadIdx.x;   // 4096 threads
    const int l31  = T & 31;
    const int FIDX = T >> 5;
    const int l5 = FIDX & 1, ks = (FIDX >> 1) & 7;
    const int ct = (FIDX >> 4) & 3, colhalf = FIDX >> 6;
    const int kb = colhalf * 128 + ks * 16 + l5 * 8;
    const int n  = ct * 32 + l31;
    bf16x8 v;
#pragma unroll
    for (int j = 0; j < 8; ++j) v[j] = (__bf16)W1[(kb + j) * HID + n];
    *(bf16x8*)(w1tf + (size_t)T * 8) = v;
}

// ---------------- K1: node GEMM, dense-staged h tile ----------------
__global__ __launch_bounds__(256, 2) void node_gemm_kernel(
    const float* __restrict__ h, const unsigned short* __restrict__ w1tf,
    const float* __restrict__ b1, unsigned short* __restrict__ uvs)
{
    // A tile: 32 rows x 128 bf16 = 256 B/row, 8 KB. 16B slots XOR-swizzled
    // by (row&7)<<4 (bijective within the 256-B row).
    __shared__ unsigned char smem[8192];

    const int t = threadIdx.x, lane = t & 63, wv = t >> 6;
    const int l31 = lane & 31, l5 = lane >> 5;
    const int group = blockIdx.x;

    // ---- stage h tile: DENSE. task tau: row r=tau>>4, slot s=tau&15.
    {
        const float* hb = h + (size_t)group * 32 * HID;
        const bool tail = (group == NGRP - 1);
#pragma unroll
        for (int it = 0; it < 2; ++it) {
            const int tau = it * 256 + t;
            const int r = tau >> 4, s = tau & 15;
            const float* src_;
            if (tail) {
                const int node = group * 32 + r;
                const int rc = (node < NNODE) ? r : (NNODE - 1 - group * 32);
                src_ = hb + rc * HID + s * 8;
            } else {
                src_ = hb + tau * 8;
            }
            float4 f0 = *(const float4*)src_;
            float4 f1 = *(const float4*)(src_ + 4);
            bf16x8 v;
            v[0] = (__bf16)f0.x; v[1] = (__bf16)f0.y;
            v[2] = (__bf16)f0.z; v[3] = (__bf16)f0.w;
            v[4] = (__bf16)f1.x; v[5] = (__bf16)f1.y;
            v[6] = (__bf16)f1.z; v[7] = (__bf16)f1.w;
            *(bf16x8*)(smem + r * 256 + ((s * 16) ^ ((r & 7) << 4))) = v;
        }
    }
    __syncthreads();

    const int colhalf = wv >> 1;            // 0 -> u cols, 1 -> v cols
    const int ctpair  = wv & 1;             // 64-col slice within the half

    float b1v[2];
#pragma unroll
    for (int cc = 0; cc < 2; ++cc)
        b1v[cc] = (colhalf == 0) ? b1[(ctpair * 2 + cc) * 32 + l31] : 0.0f;

    f32x16 acc[2];
#pragma unroll
    for (int cc = 0; cc < 2; ++cc)
#pragma unroll
        for (int r = 0; r < 16; ++r) acc[cc][r] = 0.0f;

    const int abase = l31 * 256;
    const int aswz  = (l31 & 7) << 4;

#pragma unroll
    for (int ks = 0; ks < 8; ++ks) {
        // A-frag: row=l31, k = ks*16 + l5*8 + j -> byte off ks*32 + l5*16
        bf16x8 af = *(const bf16x8*)(smem + abase +
                                     ((ks * 32 + l5 * 16) ^ aswz));
#pragma unroll
        for (int cc = 0; cc < 2; ++cc) {
            const int fidx = ((colhalf * 4 + ctpair * 2 + cc) * 8 + ks) * 2 + l5;
            bf16x8 bfg = *(const bf16x8*)(w1tf + (size_t)fidx * 256 + l31 * 8);
            acc[cc] = __builtin_amdgcn_mfma_f32_32x32x16_bf16(af, bfg,
                                                              acc[cc], 0, 0, 0);
        }
    }

    // store: C row rr=(r&3)+8*(r>>2)+4*l5 (node), col = colhalf*128 +
    // (ctpair*2+cc)*32 + l31. pair-pack -> 4B stores, 2 lines/instr.
#pragma unroll
    for (int cc = 0; cc < 2; ++cc) {
#pragma unroll
        for (int r = 0; r < 16; ++r) {
            float mine = acc[cc][r] + b1v[cc];
            float partner = __shfl_xor(mine, 1);
            if (!(l31 & 1)) {
                const int rr = (r & 3) + 8 * (r >> 2) + 4 * l5;
                const int nd = group * 32 + rr;
                if (nd < NNODE) {
                    const int n = colhalf * 128 + (ctpair * 2 + cc) * 32 + l31;
                    *(unsigned int*)(uvs + (size_t)nd * 256 + n) =
                        pack2bf(mine, partner);
                }
            }
        }
    }
}

// ---------------- K2: edge gather + tiny MLP tail (R8 exact) ----------------
__global__ __launch_bounds__(256, 8) void edge_score_kernel(
    const unsigned short* __restrict__ uvs,
    const float* __restrict__ W2, const float* __restrict__ b2,
    const int* __restrict__ src, const int* __restrict__ dst,
    float* __restrict__ out)
{
    const int t = threadIdx.x, lane = t & 63, wv = t >> 6;
    const int c = lane & 15;        // 16-B chunk within 128-col half
    const int g = lane >> 4;        // edge-in-quad 0..3

    bool idx64;
    {
        unsigned long long m =
            __ballot((src[2 * lane + 1] == 0) && (dst[2 * lane + 1] == 0));
        idx64 = (m == ~0ULL);
    }

    float w2f[8];
#pragma unroll
    for (int j = 0; j < 8; ++j) w2f[j] = W2[c * 8 + j];
    const float b2s = b2[0];

    const int gw = blockIdx.x * 4 + wv;
    const int NW = K2BLK * 4;
    const int NQ = NEDGE / 4;

    for (int q0 = gw; q0 < NQ; q0 += 2 * NW) {
        const int q1  = q0 + NW;
        const int q1c = q1 < NQ ? q1 : NQ - 1;
        const int e0  = q0 * 4 + g;
        const int e1  = q1c * 4 + g;

        const int ns0 = idx64 ? src[2 * e0] : src[e0];
        const int nd0 = idx64 ? dst[2 * e0] : dst[e0];
        const int ns1 = idx64 ? src[2 * e1] : src[e1];
        const int nd1 = idx64 ? dst[2 * e1] : dst[e1];

        const uint4 qu0 = *(const uint4*)(uvs + (size_t)ns0 * 256 + c * 8);
        const uint4 qv0 = *(const uint4*)(uvs + (size_t)nd0 * 256 + 128 + c * 8);
        const uint4 qu1 = *(const uint4*)(uvs + (size_t)ns1 * 256 + c * 8);
        const uint4 qv1 = *(const uint4*)(uvs + (size_t)nd1 * 256 + 128 + c * 8);

#pragma unroll
        for (int half = 0; half < 2; ++half) {
            const uint4 qu = half ? qu1 : qu0;
            const uint4 qv = half ? qv1 : qv0;
            float p = 0.0f;
#pragma unroll
            for (int j = 0; j < 4; ++j) {
                const unsigned int uw = j == 0 ? qu.x : j == 1 ? qu.y
                                      : j == 2 ? qu.z : qu.w;
                const unsigned int vw = j == 0 ? qv.x : j == 1 ? qv.y
                                      : j == 2 ? qv.z : qv.w;
                float slo = __uint_as_float(uw << 16)
                          + __uint_as_float(vw << 16);
                float shi = __uint_as_float(uw & 0xFFFF0000u)
                          + __uint_as_float(vw & 0xFFFF0000u);
                slo = slo > 0.0f ? slo : 0.0f;
                shi = shi > 0.0f ? shi : 0.0f;
                p = fmaf(slo, w2f[2 * j], p);
                p = fmaf(shi, w2f[2 * j + 1], p);
            }
            p += __shfl_xor(p, 1);
            p += __shfl_xor(p, 2);
            p += __shfl_xor(p, 4);
            p += __shfl_xor(p, 8);

            if (c == 0 && (half == 0 || q1 < NQ)) {
                const int e = half ? e1 : e0;
                out[e] = 1.0f / (1.0f + __expf(-(p + b2s)));
            }
        }
    }
}

// ---------------- fallback (proven single-kernel) ----------------
__global__ __launch_bounds__(256, 1) void edge_mlp_fallback(
    const float* __restrict__ h,  const float* __restrict__ W1,
    const float* __restrict__ b1, const float* __restrict__ W2,
    const float* __restrict__ b2, const int* __restrict__ src,
    const int* __restrict__ dst,  float* __restrict__ out)
{
    __shared__ unsigned char smem[65536];
    const int t = threadIdx.x, lane = t & 63, wv = t >> 6;
    const int l31 = lane & 31, l5 = lane >> 5;
    bool idx64;
    {
        unsigned long long m =
            __ballot((src[2 * lane + 1] == 0) && (dst[2 * lane + 1] == 0));
        idx64 = (m == ~0ULL);
    }
    for (int task = t; task < 4096; task += 256) {
        int n = task & 127, slot = task >> 7;
        const float* wp = W1 + (slot * 8) * HID + n;
        bf16x8 v;
#pragma unroll
        for (int j = 0; j < 8; ++j) v[j] = (__bf16)wp[j * HID];
        *(bf16x8*)(smem + n * 512 + ((slot * 16) ^ ((n & 31) << 4))) = v;
    }
    float b1v[4], w2v[4];
#pragma unroll
    for (int ct = 0; ct < 4; ++ct) {
        int n = ct * 32 + l31;
        b1v[ct] = b1[n]; w2v[ct] = W2[n];
    }
    const float b2s = b2[0];
    __syncthreads();
    const int swz = l31 << 4;
    const int gw = blockIdx.x * 4 + wv;
    for (int tile = gw; tile < NEDGE / 32; tile += 512 * 4) {
        const int e = tile * 32 + l31;
        const long long ns = idx64 ? (long long)src[2 * e] : (long long)src[e];
        const long long nd = idx64 ? (long long)dst[2 * e] : (long long)dst[e];
        const float* hs = h + ns * HID + l5 * 8;
        const float* hd = h + nd * HID + l5 * 8;
        f32x16 acc[4];
#pragma unroll
        for (int ct = 0; ct < 4; ++ct)
#pragma unroll
            for (int r = 0; r < 16; ++r) acc[ct][r] = 0.0f;
#pragma unroll
        for (int ks = 0; ks < 16; ++ks) {
            const float* p = (ks < 8) ? (hs + ks * 16) : (hd + (ks - 8) * 16);
            float4 f0 = *(const float4*)p;
            float4 f1 = *(const float4*)(p + 4);
            bf16x8 af;
            af[0] = (__bf16)f0.x; af[1] = (__bf16)f0.y;
            af[2] = (__bf16)f0.z; af[3] = (__bf16)f0.w;
            af[4] = (__bf16)f1.x; af[5] = (__bf16)f1.y;
            af[6] = (__bf16)f1.z; af[7] = (__bf16)f1.w;
            const int coff = ks * 32 + l5 * 16;
#pragma unroll
            for (int ct = 0; ct < 4; ++ct) {
                const int n = ct * 32 + l31;
                bf16x8 bfg = *(const bf16x8*)(smem + n * 512 + (coff ^ swz));
                acc[ct] = __builtin_amdgcn_mfma_f32_32x32x16_bf16(af, bfg,
                                                                  acc[ct], 0, 0, 0);
            }
        }
        float p[16];
#pragma unroll
        for (int r = 0; r < 16; ++r) p[r] = 0.0f;
#pragma unroll
        for (int ct = 0; ct < 4; ++ct)
#pragma unroll
            for (int r = 0; r < 16; ++r) {
                float v = acc[ct][r] + b1v[ct];
                v = v > 0.0f ? v : 0.0f;
                p[r] += v * w2v[ct];
            }
#pragma unroll
        for (int r = 0; r < 16; ++r) {
            p[r] += __shfl_xor(p[r], 1);  p[r] += __shfl_xor(p[r], 2);
            p[r] += __shfl_xor(p[r], 4);  p[r] += __shfl_xor(p[r], 8);
            p[r] += __shfl_xor(p[r], 16);
        }
        if (l31 == 0) {
#pragma unroll
            for (int g = 0; g < 4; ++g) {
                const int e0 = tile * 32 + g * 8 + l5 * 4;
                float4 o4;
                o4.x = 1.0f / (1.0f + __expf(-(p[4 * g + 0] + b2s)));
                o4.y = 1.0f / (1.0f + __expf(-(p[4 * g + 1] + b2s)));
                o4.z = 1.0f / (1.0f + __expf(-(p[4 * g + 2] + b2s)));
                o4.w = 1.0f / (1.0f + __expf(-(p[4 * g + 3] + b2s)));
                *(float4*)(out + e0) = o4;
            }
        }
    }
}

extern "C" void kernel_launch(void* const* d_in, const int* in_sizes, int n_in,
                              void* d_out, int out_size, void* d_ws, size_t ws_size,
                              hipStream_t stream) {
    const float* h  = (const float*)d_in[0];
    const float* W1 = (const float*)d_in[1];
    const float* b1 = (const float*)d_in[2];
    const float* W2 = (const float*)d_in[3];
    const float* b2 = (const float*)d_in[4];
    const int* src  = (const int*)d_in[5];
    const int* dst  = (const int*)d_in[6];
    (void)in_sizes; (void)n_in; (void)out_size;

    const size_t need = WTFRAG_OFF + 65536;
    if (ws_size >= need) {
        unsigned short* uvs  = (unsigned short*)d_ws;
        unsigned short* w1tf = (unsigned short*)((char*)d_ws + WTFRAG_OFF);
        w1_frag_kernel<<<16, 256, 0, stream>>>(W1, w1tf);
        node_gemm_kernel<<<NGRP, 256, 0, stream>>>(h, w1tf, b1, uvs);
        edge_score_kernel<<<K2BLK, 256, 0, stream>>>(uvs, W2, b2, src, dst,
                                                     (float*)d_out);
    } else {
        edge_mlp_fallback<<<512, 256, 0, stream>>>(h, W1, b1, W2, b2, src, dst,
                                                   (float*)d_out);
    }
}